// Round 1
// baseline (6058.063 us; speedup 1.0000x reference)
//
#include <hip/hip_runtime.h>
#include <stdint.h>

// Problem: V=50257 E=256 H=512 O=50257 B=8 T=512
// Phases: [A] xg = emb[idx] @ W_ih^T + b  (fp32, 4.3GF)
//         [D] fc_w -> bf16 (padded to 50304 rows)
//         [B] 512-step LSTM recurrence, 128 persistent blocks + spin barrier
//         [C] logits = hseq(bf16) @ fc_w(bf16)^T + fc_b   (211GF, MFMA)
// ws layout (bytes):
//   xg      @ 0          : 512*2048*8*4   = 33,554,432   [T][4H][B] fp32
//   hseq    @ 33,554,432 : 4096*512*2     =  4,194,304   [B*T][H] bf16
//   fcw_bf  @ 37,748,736 : 50304*512*2    = 51,511,296   padded bf16
//   h_buf   @ 89,260,032 : 2*4096*4       =     32,768   double-buffered h
//   counter @ 89,292,800 : 64             barrier counter (memset 0 each launch)

#define E_ 256
#define H_ 512
#define O_ 50257
#define B_ 8
#define T_ 512
#define G4 2048
#define M_ 4096
#define NPAD 50304
#define NBLK 128

typedef __attribute__((ext_vector_type(4))) float f32x4;
typedef __attribute__((ext_vector_type(8))) short short8;

__device__ __forceinline__ ushort f2bf(float f) {
  union { float f; uint32_t u; } x; x.f = f;
  uint32_t r = (x.u + 0x7fffu + ((x.u >> 16) & 1u)) >> 16;  // RNE
  return (ushort)r;
}

// ---------------- [A] xg GEMM: M=4096 N=2048 K=256, A rows gathered from emb
__global__ void __launch_bounds__(256) xg_kernel(
    const int* __restrict__ idx, const float* __restrict__ emb,
    const float* __restrict__ Wih, const float* __restrict__ bih,
    const float* __restrict__ bhh, float* __restrict__ xg) {
  __shared__ float As[64][68];   // +4 pad: bank spread
  __shared__ float Bs[64][68];
  __shared__ int idxl[64];
  const int t = threadIdx.x;
  const int m0 = blockIdx.y * 64, n0 = blockIdx.x * 64;
  if (t < 64) idxl[t] = idx[m0 + t];
  __syncthreads();
  float acc[4][4] = {};
  const int tx = t & 15, ty = t >> 4;
  for (int kt = 0; kt < 256; kt += 64) {
    for (int c = t; c < 1024; c += 256) {          // 64 rows x 16 chunks(16B)
      const int r = c >> 4, s = (c & 15) << 2;
      *(float4*)&As[r][s] = *(const float4*)&emb[(size_t)idxl[r] * E_ + kt + s];
      *(float4*)&Bs[r][s] = *(const float4*)&Wih[(size_t)(n0 + r) * E_ + kt + s];
    }
    __syncthreads();
#pragma unroll
    for (int kk = 0; kk < 64; kk += 4) {
      float4 a[4], b[4];
#pragma unroll
      for (int u = 0; u < 4; ++u) a[u] = *(const float4*)&As[ty * 4 + u][kk];
#pragma unroll
      for (int v = 0; v < 4; ++v) b[v] = *(const float4*)&Bs[tx * 4 + v][kk];
#pragma unroll
      for (int u = 0; u < 4; ++u)
#pragma unroll
        for (int v = 0; v < 4; ++v)
          acc[u][v] += a[u].x * b[v].x + a[u].y * b[v].y +
                       a[u].z * b[v].z + a[u].w * b[v].w;
    }
    __syncthreads();
  }
#pragma unroll
  for (int u = 0; u < 4; ++u) {
    const int m = m0 + ty * 4 + u;
    const int bb = m >> 9, st = m & 511;           // m = b*T + t
#pragma unroll
    for (int v = 0; v < 4; ++v) {
      const int n = n0 + tx * 4 + v;
      // layout [T][4H][B] so the recurrence reads contiguous-ish per step
      xg[((size_t)st * G4 + n) * B_ + bb] = acc[u][v] + bih[n] + bhh[n];
    }
  }
}

// ---------------- [D] fc_w fp32 -> bf16, padded rows [50257,50304) zeroed
__global__ void __launch_bounds__(256) conv_kernel(const float* __restrict__ w,
                                                   ushort* __restrict__ o) {
  const size_t NV = (size_t)NPAD * 512 / 4;
  const size_t LIM = (size_t)O_ * 512;
  for (size_t i = (size_t)blockIdx.x * 256 + threadIdx.x; i < NV;
       i += (size_t)gridDim.x * 256) {
    const size_t e = i << 2;
    ushort4 r;
    if (e < LIM) {
      const float4 v = *(const float4*)&w[e];
      r.x = f2bf(v.x); r.y = f2bf(v.y); r.z = f2bf(v.z); r.w = f2bf(v.w);
    } else {
      r.x = r.y = r.z = r.w = 0;
    }
    *(ushort4*)&o[e] = r;
  }
}

// ---------------- [B] LSTM recurrence: 128 blocks, block owns 4 hidden cols
// thread t: d=t&127, combo=d>>3 (g*4+jj, 16 combos), b=d&7, half=t>>7 (k-split)
__global__ void __launch_bounds__(256) lstm_kernel(
    const float* __restrict__ h0, const float* __restrict__ c0,
    const float* __restrict__ Whh, const float* __restrict__ xg,
    float* __restrict__ hb, unsigned* __restrict__ cnt,
    ushort* __restrict__ hseq, float* __restrict__ tail) {
  __shared__ float Wl[16 * 516];   // 16 W_hh rows, +4 pad (516%32=4 -> banks spread)
  __shared__ float hl[8 * 516];    // staged h, all batches
  __shared__ float part[256];
  __shared__ float gates[128];
  const int t = threadIdx.x;
  const int j0 = blockIdx.x << 2;
  // stage this block's 16 W_hh rows (g in {i,f,g,o} x jj in 0..3) once
  for (int i = t; i < 16 * 512; i += 256) {
    const int row = i >> 9, k = i & 511;
    const int g = row >> 2, jj = row & 3;
    Wl[row * 516 + k] = Whh[(size_t)((g << 9) + j0 + jj) * 512 + k];
  }
  const int d = t & 127;
  const int combo = d >> 3, bb = d & 7;
  const int kb = (t >> 7) << 8;                 // half * 256
  const int ujj = t >> 3, ub = t & 7;           // for update threads t<32
  float c_reg = (t < 32) ? c0[(size_t)ub * 512 + j0 + ujj] : 0.f;
  const float4* wrow = (const float4*)&Wl[combo * 516 + kb];
  const float4* hrow = (const float4*)&hl[bb * 516 + kb];

  for (int step = 0; step < 512; ++step) {
    // stage h (coherent agent loads after step 0: h crosses XCDs)
    if (step == 0) {
#pragma unroll
      for (int i = t, n = 0; n < 16; i += 256, ++n)
        hl[(i >> 9) * 516 + (i & 511)] = h0[i];
    } else {
      const float* hs = hb + ((step & 1) << 12);
#pragma unroll
      for (int i = t, n = 0; n < 16; i += 256, ++n)
        hl[(i >> 9) * 516 + (i & 511)] =
            __hip_atomic_load(&hs[i], __ATOMIC_RELAXED, __HIP_MEMORY_SCOPE_AGENT);
    }
    __syncthreads();
    // half-dot: 64 float4 MACs, 4 independent chains (avoid serial FMA latency)
    float a0 = 0.f, a1 = 0.f, a2 = 0.f, a3 = 0.f;
#pragma unroll 8
    for (int k = 0; k < 64; ++k) {
      const float4 w4 = wrow[k], h4 = hrow[k];
      a0 += w4.x * h4.x; a1 += w4.y * h4.y;
      a2 += w4.z * h4.z; a3 += w4.w * h4.w;
    }
    part[t] = (a0 + a1) + (a2 + a3);
    __syncthreads();
    if (t < 128)
      gates[t] = part[t] + part[t + 128] +
                 xg[((size_t)step * G4 + (combo >> 2) * 512 + j0 + (combo & 3)) * B_ + bb];
    __syncthreads();
    if (t < 32) {
      const float gi = gates[(ujj << 3) + ub];
      const float gf = gates[((4 + ujj) << 3) + ub];
      const float gg = gates[((8 + ujj) << 3) + ub];
      const float go = gates[((12 + ujj) << 3) + ub];
      const float si = 1.f / (1.f + expf(-gi));
      const float sf = 1.f / (1.f + expf(-gf));
      const float so = 1.f / (1.f + expf(-go));
      c_reg = sf * c_reg + si * tanhf(gg);
      const float h = so * tanhf(c_reg);
      const int col = j0 + ujj;
      __hip_atomic_store(&hb[(((step + 1) & 1) << 12) + (ub << 9) + col], h,
                         __ATOMIC_RELAXED, __HIP_MEMORY_SCOPE_AGENT);
      hseq[((size_t)(ub * 512 + step) << 9) + col] = f2bf(h);
      if (step == 511) {
        tail[(ub << 9) + col] = h;            // h_n
        tail[4096 + (ub << 9) + col] = c_reg; // c_n
      }
    }
    if (step < 511) {
      // drain h stores (wave0 lanes 0-31 wrote; lane0 arrives after)
      asm volatile("s_waitcnt vmcnt(0)" ::: "memory");
      if (t == 0) {
        __hip_atomic_fetch_add(cnt, 1u, __ATOMIC_RELAXED, __HIP_MEMORY_SCOPE_AGENT);
        const unsigned target = (unsigned)NBLK * (unsigned)(step + 1);
        while (__hip_atomic_load(cnt, __ATOMIC_RELAXED, __HIP_MEMORY_SCOPE_AGENT) < target)
          __builtin_amdgcn_s_sleep(1);
      }
      __syncthreads();
    }
  }
}

// ---------------- [C] FC: [4096,512]bf16 x [50304,512]bf16^T -> fp32 logits
#if defined(__has_builtin)
#if __has_builtin(__builtin_amdgcn_global_load_lds)
#define HAS_GLL 1
#endif
#endif

__device__ __forceinline__ void gll16(const void* g, void* l) {
#ifdef HAS_GLL
  __builtin_amdgcn_global_load_lds(
      (const __attribute__((address_space(1))) void*)g,
      (__attribute__((address_space(3))) void*)l, 16, 0, 0);
#endif
}

__global__ void __launch_bounds__(256) fc_kernel(
    const ushort* __restrict__ A, const ushort* __restrict__ Bm,
    const float* __restrict__ bias, float* __restrict__ out) {
  __shared__ ushort As[128 * 64];
  __shared__ ushort Bs[128 * 64];
  const int bid = blockIdx.x;
  // XCD-chunked swizzle: 12576 = 8 * 1572; m-fastest inside chunk (B-tile reuse)
  const int wg = (bid & 7) * 1572 + (bid >> 3);
  const int mt = wg & 31, nt = wg >> 5;
  const int m0 = mt << 7, n0 = nt << 7;
  const int t = threadIdx.x, l = t & 63, w = t >> 6;
  const int wm = w >> 1, wn = w & 1;
  const int lr = l & 15, lk = (l >> 4) << 3;
  f32x4 acc[4][4];
#pragma unroll
  for (int i = 0; i < 4; ++i)
#pragma unroll
    for (int j = 0; j < 4; ++j) acc[i][j] = {0.f, 0.f, 0.f, 0.f};

  for (int kt = 0; kt < 512; kt += 64) {
#ifdef HAS_GLL
#pragma unroll
    for (int it = 0; it < 4; ++it) {
      const int cb = it * 256 + w * 64;            // wave-uniform chunk base
      const int chunk = cb + l;
      const int r = chunk >> 3, k8 = (chunk & 7) << 3;
      gll16(&A[(size_t)(m0 + r) * 512 + kt + k8], &As[cb * 8]);
      gll16(&Bm[(size_t)(n0 + r) * 512 + kt + k8], &Bs[cb * 8]);
    }
#else
    for (int c = t; c < 1024; c += 256) {
      const int r = c >> 3, k8 = (c & 7) << 3;
      *(short8*)&As[r * 64 + k8] = *(const short8*)&A[(size_t)(m0 + r) * 512 + kt + k8];
      *(short8*)&Bs[r * 64 + k8] = *(const short8*)&Bm[(size_t)(n0 + r) * 512 + kt + k8];
    }
#endif
    __syncthreads();
#pragma unroll
    for (int kk = 0; kk < 2; ++kk) {
      short8 af[4], bf[4];
#pragma unroll
      for (int f = 0; f < 4; ++f) {
        af[f] = *(const short8*)&As[(wm * 64 + f * 16 + lr) * 64 + kk * 32 + lk];
        bf[f] = *(const short8*)&Bs[(wn * 64 + f * 16 + lr) * 64 + kk * 32 + lk];
      }
#pragma unroll
      for (int fm = 0; fm < 4; ++fm)
#pragma unroll
        for (int fn = 0; fn < 4; ++fn)
          acc[fm][fn] = __builtin_amdgcn_mfma_f32_16x16x32_bf16(
              af[fm], bf[fn], acc[fm][fn], 0, 0, 0);
    }
    __syncthreads();
  }
  // C/D layout (m89/m91): col = lane&15, row = (lane>>4)*4 + reg
#pragma unroll
  for (int fn = 0; fn < 4; ++fn) {
    const int col = n0 + wn * 64 + fn * 16 + lr;
    if (col < O_) {
      const float bv = bias[col];
#pragma unroll
      for (int fm = 0; fm < 4; ++fm) {
        const int rbase = m0 + wm * 64 + fm * 16 + ((l >> 4) << 2);
#pragma unroll
        for (int q = 0; q < 4; ++q)
          out[(size_t)(rbase + q) * O_ + col] = acc[fm][fn][q] + bv;
      }
    }
  }
}

extern "C" void kernel_launch(void* const* d_in, const int* in_sizes, int n_in,
                              void* d_out, int out_size, void* d_ws, size_t ws_size,
                              hipStream_t stream) {
  const int*   idx = (const int*)d_in[0];
  const float* h0  = (const float*)d_in[1];
  const float* c0  = (const float*)d_in[2];
  const float* emb = (const float*)d_in[3];
  const float* Wih = (const float*)d_in[4];
  const float* Whh = (const float*)d_in[5];
  const float* bih = (const float*)d_in[6];
  const float* bhh = (const float*)d_in[7];
  const float* fcw = (const float*)d_in[8];
  const float* fcb = (const float*)d_in[9];
  float* out = (float*)d_out;

  char* ws = (char*)d_ws;
  float*    xg   = (float*)(ws + 0);
  ushort*   hseq = (ushort*)(ws + 33554432);
  ushort*   fbw  = (ushort*)(ws + 37748736);
  float*    hb   = (float*)(ws + 89260032);
  unsigned* cnt  = (unsigned*)(ws + 89292800);

  hipMemsetAsync(cnt, 0, 64, stream);  // barrier counter must start at 0
  xg_kernel<<<dim3(32, 64), 256, 0, stream>>>(idx, emb, Wih, bih, bhh, xg);
  conv_kernel<<<2048, 256, 0, stream>>>(fcw, fbw);
  lstm_kernel<<<NBLK, 256, 0, stream>>>(h0, c0, Whh, xg, hb, cnt, hseq,
                                        out + (size_t)M_ * O_);
  fc_kernel<<<32 * 393, 256, 0, stream>>>(hseq, fbw, fcb, out);
}

// Round 5
// 4021.222 us; speedup vs baseline: 1.5065x; 1.5065x over previous
//
#include <hip/hip_runtime.h>
#include <stdint.h>

// Problem: V=50257 E=256 H=512 O=50257 B=8 T=512
// Phases: [A] xg = emb[idx] @ W_ih^T + b  (fp32, 4.3GF)
//         [D] fc_w -> bf16 (padded to 50304 rows)
//         [B] 512-step LSTM recurrence, 64 persistent blocks, split-bf16 MFMA,
//             W_hh in registers, distributed-flag barrier (no atomic RMW,
//             bounded spin: a wedged barrier finishes in ~1s with wrong
//             output instead of hanging the container)
//         [C] logits = hseq(bf16) @ fc_w(bf16)^T + fc_b   (211GF, MFMA)
// ws layout (bytes):
//   xg      @ 0          : 512*2048*8*4   = 33,554,432   [T][4H][B] fp32
//   hseq    @ 33,554,432 : 4096*512*2     =  4,194,304   [b*T+t][H] bf16
//   fcw_bf  @ 37,748,736 : 50304*512*2    = 51,511,296   padded bf16
//   hbu     @ 89,260,032 : 2buf*2plane*8b*256 uints = 32,768  h hi/lo bf16 pairs
//   flags   @ 89,292,800 : 256            per-block step flags (memset 0)

#define E_ 256
#define H_ 512
#define O_ 50257
#define B_ 8
#define T_ 512
#define G4 2048
#define M_ 4096
#define NPAD 50304
#define NBLK_L 64

typedef __attribute__((ext_vector_type(4))) float f32x4;
typedef __attribute__((ext_vector_type(8))) short short8;

__device__ __forceinline__ ushort f2bf(float f) {
  union { float f; uint32_t u; } x; x.f = f;
  uint32_t r = (x.u + 0x7fffu + ((x.u >> 16) & 1u)) >> 16;  // RNE
  return (ushort)r;
}
__device__ __forceinline__ float bf2f(ushort h) {
  union { uint32_t u; float f; } x; x.u = (uint32_t)h << 16;
  return x.f;
}

// ---------------- [A] xg GEMM: M=4096 N=2048 K=256, A rows gathered from emb
__global__ void __launch_bounds__(256) xg_kernel(
    const int* __restrict__ idx, const float* __restrict__ emb,
    const float* __restrict__ Wih, const float* __restrict__ bih,
    const float* __restrict__ bhh, float* __restrict__ xg) {
  __shared__ float As[64][68];
  __shared__ float Bs[64][68];
  __shared__ int idxl[64];
  const int t = threadIdx.x;
  const int m0 = blockIdx.y * 64, n0 = blockIdx.x * 64;
  if (t < 64) idxl[t] = idx[m0 + t];
  __syncthreads();
  float acc[4][4] = {};
  const int tx = t & 15, ty = t >> 4;
  for (int kt = 0; kt < 256; kt += 64) {
    for (int c = t; c < 1024; c += 256) {
      const int r = c >> 4, s = (c & 15) << 2;
      *(float4*)&As[r][s] = *(const float4*)&emb[(size_t)idxl[r] * E_ + kt + s];
      *(float4*)&Bs[r][s] = *(const float4*)&Wih[(size_t)(n0 + r) * E_ + kt + s];
    }
    __syncthreads();
#pragma unroll
    for (int kk = 0; kk < 64; kk += 4) {
      float4 a[4], b[4];
#pragma unroll
      for (int u = 0; u < 4; ++u) a[u] = *(const float4*)&As[ty * 4 + u][kk];
#pragma unroll
      for (int v = 0; v < 4; ++v) b[v] = *(const float4*)&Bs[tx * 4 + v][kk];
#pragma unroll
      for (int u = 0; u < 4; ++u)
#pragma unroll
        for (int v = 0; v < 4; ++v)
          acc[u][v] += a[u].x * b[v].x + a[u].y * b[v].y +
                       a[u].z * b[v].z + a[u].w * b[v].w;
    }
    __syncthreads();
  }
#pragma unroll
  for (int u = 0; u < 4; ++u) {
    const int m = m0 + ty * 4 + u;
    const int bb = m >> 9, st = m & 511;
#pragma unroll
    for (int v = 0; v < 4; ++v) {
      const int n = n0 + tx * 4 + v;
      xg[((size_t)st * G4 + n) * B_ + bb] = acc[u][v] + bih[n] + bhh[n];
    }
  }
}

// ---------------- [D] fc_w fp32 -> bf16, padded rows [50257,50304) zeroed
__global__ void __launch_bounds__(256) conv_kernel(const float* __restrict__ w,
                                                   ushort* __restrict__ o) {
  const size_t NV = (size_t)NPAD * 512 / 4;
  const size_t LIM = (size_t)O_ * 512;
  for (size_t i = (size_t)blockIdx.x * 256 + threadIdx.x; i < NV;
       i += (size_t)gridDim.x * 256) {
    const size_t e = i << 2;
    ushort4 r;
    if (e < LIM) {
      const float4 v = *(const float4*)&w[e];
      r.x = f2bf(v.x); r.y = f2bf(v.y); r.z = f2bf(v.z); r.w = f2bf(v.w);
    } else {
      r.x = r.y = r.z = r.w = 0;
    }
    *(ushort4*)&o[e] = r;
  }
}

// ---------------- [B] LSTM recurrence
// 64 blocks x 256 thr. Block owns 8 hidden cols (j0..j0+7) -> 32 gate-rows,
// interleaved into 2 MFMA n-tiles. Wave w: nt = w>>1, kh = w&1 (K halves).
// W_hh B-frags (bf16 hi/lo) preloaded in registers. h exchanged via global
// packed hi/lo bf16 planes with per-block flags (monotonic step counter).
__global__ void __launch_bounds__(256) lstm_kernel(
    const float* __restrict__ h0, const float* __restrict__ c0,
    const float* __restrict__ Whh, const float* __restrict__ xg,
    unsigned* __restrict__ hbu, unsigned* __restrict__ flags,
    ushort* __restrict__ hseq, float* __restrict__ tail) {
  __shared__ ushort hi_l[8 * 528];
  __shared__ ushort lo_l[8 * 528];
  __shared__ float part_l[2][256];
  __shared__ float gates_l[256];      // [g*64 + jj*8 + b]
  const int t = threadIdx.x;
  const int w = t >> 6, l = t & 63;
  const int bid = blockIdx.x;
  const int j0 = bid << 3;
  const int slot = l & 15, u = l >> 4;
  const int nt = w >> 1, kh = w & 1;

  // preload W_hh fragments (split bf16) into registers: 8 kfrags x hi/lo
  short8 whi[8], wlo[8];
  {
    const int jj = nt * 4 + (slot >> 2);
    const int g = slot & 3;
    const size_t row = (size_t)(g * 512 + j0 + jj) * 512;
#pragma unroll
    for (int kf = 0; kf < 8; ++kf) {
      const int k0 = kh * 256 + kf * 32 + u * 8;
      float v[8];
      *(float4*)&v[0] = *(const float4*)&Whh[row + k0];
      *(float4*)&v[4] = *(const float4*)&Whh[row + k0 + 4];
      short8 hi, lo;
#pragma unroll
      for (int i = 0; i < 8; ++i) {
        const ushort hb_ = f2bf(v[i]);
        hi[i] = (short)hb_;
        lo[i] = (short)f2bf(v[i] - bf2f(hb_));
      }
      whi[kf] = hi; wlo[kf] = lo;
    }
  }

  float c_reg = (t < 64) ? c0[(size_t)(t & 7) * 512 + j0 + (t >> 3)] : 0.f;

  for (int step = 0; step < 512; ++step) {
    // xg prefetch for the update lanes (overlaps the poll)
    float xr0 = 0.f, xr1 = 0.f, xr2 = 0.f, xr3 = 0.f;
    if (t < 64) {
      const size_t xb = ((size_t)step * G4 + j0 + (t >> 3)) * B_ + (t & 7);
      xr0 = xg[xb];
      xr1 = xg[xb + 4096];
      xr2 = xg[xb + 8192];
      xr3 = xg[xb + 12288];
    }
    // wait for all blocks to have published h for this step (bounded spin:
    // legit waits are tens of iterations; 20k bound => a wedged protocol
    // terminates in ~1s/launch with wrong output instead of hanging)
    if (step > 0 && w == 0) {
      const unsigned tgt = (unsigned)step;
      for (int spin = 0; spin < 20000; ++spin) {
        const unsigned f =
            __hip_atomic_load(&flags[l], __ATOMIC_RELAXED, __HIP_MEMORY_SCOPE_AGENT);
        if (__all((int)(f >= tgt))) break;
        __builtin_amdgcn_s_sleep(1);
      }
    }
    __syncthreads();
    // stage h hi/lo planes into LDS
    if (step == 0) {
#pragma unroll
      for (int i = 0; i < 16; ++i) {
        const int idx = t * 16 + i;
        const float v = h0[idx];
        const int b = idx >> 9, k = idx & 511;
        const ushort hb_ = f2bf(v);
        hi_l[b * 528 + k] = hb_;
        lo_l[b * 528 + k] = f2bf(v - bf2f(hb_));
      }
    } else {
      const unsigned long long* src =
          (const unsigned long long*)(hbu + (size_t)(step & 1) * 4096);
#pragma unroll
      for (int i = 0; i < 8; ++i) {
        const int gu = i * 256 + t;                 // coalesced, plane-uniform per i
        const unsigned long long val =
            __hip_atomic_load(&src[gu], __ATOMIC_RELAXED, __HIP_MEMORY_SCOPE_AGENT);
        const int v = gu & 1023;
        const int b = v >> 7, j = (v & 127) * 4;
        ushort* dst = (gu >> 10) ? lo_l : hi_l;
        *(unsigned long long*)&dst[b * 528 + j] = val;
      }
    }
    __syncthreads();
    // MFMA over this wave's k-half: acc[n-slot (gate-row), m (batch)]
    f32x4 acc = {0.f, 0.f, 0.f, 0.f};
    {
      const int kbase = kh * 256 + u * 8;
#pragma unroll
      for (int kf = 0; kf < 8; ++kf) {
        short8 ahi = {0, 0, 0, 0, 0, 0, 0, 0};
        short8 alo = {0, 0, 0, 0, 0, 0, 0, 0};
        if (slot < 8) {
          ahi = *(const short8*)&hi_l[slot * 528 + kbase + kf * 32];
          alo = *(const short8*)&lo_l[slot * 528 + kbase + kf * 32];
        }
        acc = __builtin_amdgcn_mfma_f32_16x16x32_bf16(ahi, whi[kf], acc, 0, 0, 0);
        acc = __builtin_amdgcn_mfma_f32_16x16x32_bf16(ahi, wlo[kf], acc, 0, 0, 0);
        acc = __builtin_amdgcn_mfma_f32_16x16x32_bf16(alo, whi[kf], acc, 0, 0, 0);
      }
    }
    // merge k-halves: waves 1,3 dump, waves 0,2 add + scatter gates
    if (kh == 1) *(f32x4*)&part_l[nt][l * 4] = acc;
    __syncthreads();
    if (kh == 0) {
      const f32x4 o = *(const f32x4*)&part_l[nt][l * 4];
      acc += o;
      if (u < 2) {
        const int jj = nt * 4 + (slot >> 2), g = slot & 3;
#pragma unroll
        for (int q = 0; q < 4; ++q)
          gates_l[g * 64 + jj * 8 + (u * 4 + q)] = acc[q];
      }
    }
    __syncthreads();
    // epilogue: wave 0, one (col jj, batch b) per lane
    if (t < 64) {
      const int jj = t >> 3, b = t & 7;
      const float gi = gates_l[jj * 8 + b] + xr0;
      const float gf = gates_l[64 + jj * 8 + b] + xr1;
      const float gg = gates_l[128 + jj * 8 + b] + xr2;
      const float go = gates_l[192 + jj * 8 + b] + xr3;
      const float si = 1.f / (1.f + expf(-gi));
      const float sf = 1.f / (1.f + expf(-gf));
      const float so = 1.f / (1.f + expf(-go));
      c_reg = sf * c_reg + si * tanhf(gg);
      const float h = so * tanhf(c_reg);
      const ushort hh = f2bf(h);
      const ushort hl = f2bf(h - bf2f(hh));
      hseq[((size_t)b * 512 + step) * 512 + j0 + jj] = hh;
      const unsigned nhi = (unsigned)__shfl_down((int)hh, 8);
      const unsigned nlo = (unsigned)__shfl_down((int)hl, 8);
      if ((jj & 1) == 0 && step < 511) {
        const unsigned jp = (unsigned)(j0 + jj) >> 1;
        const unsigned boff = ((step + 1) & 1) * 4096;
        __hip_atomic_store(&hbu[boff + b * 256 + jp],
                           (unsigned)hh | (nhi << 16),
                           __ATOMIC_RELAXED, __HIP_MEMORY_SCOPE_AGENT);
        __hip_atomic_store(&hbu[boff + 2048 + b * 256 + jp],
                           (unsigned)hl | (nlo << 16),
                           __ATOMIC_RELAXED, __HIP_MEMORY_SCOPE_AGENT);
      }
      if (step == 511) {
        tail[(b << 9) + j0 + jj] = h;
        tail[4096 + (b << 9) + j0 + jj] = c_reg;
      }
    }
    if (step < 511 && w == 0) {
      asm volatile("s_waitcnt vmcnt(0)" ::: "memory");   // h visible before flag
      if (t == 0)
        __hip_atomic_store(&flags[bid], (unsigned)(step + 1),
                           __ATOMIC_RELAXED, __HIP_MEMORY_SCOPE_AGENT);
    }
  }
}

// ---------------- [C] FC: [4096,512]bf16 x [50304,512]bf16^T -> fp32 logits
#if defined(__has_builtin)
#if __has_builtin(__builtin_amdgcn_global_load_lds)
#define HAS_GLL 1
#endif
#endif

__device__ __forceinline__ void gll16(const void* g, void* l) {
#ifdef HAS_GLL
  __builtin_amdgcn_global_load_lds(
      (const __attribute__((address_space(1))) void*)g,
      (__attribute__((address_space(3))) void*)l, 16, 0, 0);
#endif
}

__global__ void __launch_bounds__(256) fc_kernel(
    const ushort* __restrict__ A, const ushort* __restrict__ Bm,
    const float* __restrict__ bias, float* __restrict__ out) {
  __shared__ ushort As[128 * 64];
  __shared__ ushort Bs[128 * 64];
  const int bid = blockIdx.x;
  const int wg = (bid & 7) * 1572 + (bid >> 3);
  const int mt = wg & 31, nt = wg >> 5;
  const int m0 = mt << 7, n0 = nt << 7;
  const int t = threadIdx.x, l = t & 63, w = t >> 6;
  const int wm = w >> 1, wn = w & 1;
  const int lr = l & 15, lk = (l >> 4) << 3;
  f32x4 acc[4][4];
#pragma unroll
  for (int i = 0; i < 4; ++i)
#pragma unroll
    for (int j = 0; j < 4; ++j) acc[i][j] = {0.f, 0.f, 0.f, 0.f};

  for (int kt = 0; kt < 512; kt += 64) {
#ifdef HAS_GLL
#pragma unroll
    for (int it = 0; it < 4; ++it) {
      const int cb = it * 256 + w * 64;
      const int chunk = cb + l;
      const int r = chunk >> 3, k8 = (chunk & 7) << 3;
      gll16(&A[(size_t)(m0 + r) * 512 + kt + k8], &As[cb * 8]);
      gll16(&Bm[(size_t)(n0 + r) * 512 + kt + k8], &Bs[cb * 8]);
    }
#else
    for (int c = t; c < 1024; c += 256) {
      const int r = c >> 3, k8 = (c & 7) << 3;
      *(short8*)&As[r * 64 + k8] = *(const short8*)&A[(size_t)(m0 + r) * 512 + kt + k8];
      *(short8*)&Bs[r * 64 + k8] = *(const short8*)&Bm[(size_t)(n0 + r) * 512 + kt + k8];
    }
#endif
    __syncthreads();
#pragma unroll
    for (int kk = 0; kk < 2; ++kk) {
      short8 af[4], bf[4];
#pragma unroll
      for (int f = 0; f < 4; ++f) {
        af[f] = *(const short8*)&As[(wm * 64 + f * 16 + lr) * 64 + kk * 32 + lk];
        bf[f] = *(const short8*)&Bs[(wn * 64 + f * 16 + lr) * 64 + kk * 32 + lk];
      }
#pragma unroll
      for (int fm = 0; fm < 4; ++fm)
#pragma unroll
        for (int fn = 0; fn < 4; ++fn)
          acc[fm][fn] = __builtin_amdgcn_mfma_f32_16x16x32_bf16(
              af[fm], bf[fn], acc[fm][fn], 0, 0, 0);
    }
    __syncthreads();
  }
#pragma unroll
  for (int fn = 0; fn < 4; ++fn) {
    const int col = n0 + wn * 64 + fn * 16 + lr;
    if (col < O_) {
      const float bv = bias[col];
#pragma unroll
      for (int fm = 0; fm < 4; ++fm) {
        const int rbase = m0 + wm * 64 + fm * 16 + ((l >> 4) << 2);
#pragma unroll
        for (int q = 0; q < 4; ++q)
          out[(size_t)(rbase + q) * O_ + col] = acc[fm][fn][q] + bv;
      }
    }
  }
}

extern "C" void kernel_launch(void* const* d_in, const int* in_sizes, int n_in,
                              void* d_out, int out_size, void* d_ws, size_t ws_size,
                              hipStream_t stream) {
  const int*   idx = (const int*)d_in[0];
  const float* h0  = (const float*)d_in[1];
  const float* c0  = (const float*)d_in[2];
  const float* emb = (const float*)d_in[3];
  const float* Wih = (const float*)d_in[4];
  const float* Whh = (const float*)d_in[5];
  const float* bih = (const float*)d_in[6];
  const float* bhh = (const float*)d_in[7];
  const float* fcw = (const float*)d_in[8];
  const float* fcb = (const float*)d_in[9];
  float* out = (float*)d_out;

  char* ws = (char*)d_ws;
  float*    xg    = (float*)(ws + 0);
  ushort*   hseq  = (ushort*)(ws + 33554432);
  ushort*   fbw   = (ushort*)(ws + 37748736);
  unsigned* hbu   = (unsigned*)(ws + 89260032);
  unsigned* flags = (unsigned*)(ws + 89292800);

  hipMemsetAsync(flags, 0, 256, stream);  // per-block step flags start at 0
  xg_kernel<<<dim3(32, 64), 256, 0, stream>>>(idx, emb, Wih, bih, bhh, xg);
  conv_kernel<<<2048, 256, 0, stream>>>(fcw, fbw);
  lstm_kernel<<<NBLK_L, 256, 0, stream>>>(h0, c0, Whh, xg, hbu, flags, hseq,
                                          out + (size_t)M_ * O_);
  fc_kernel<<<32 * 393, 256, 0, stream>>>(hseq, fbw, fcb, out);
}